// Round 1
// baseline (243.087 us; speedup 1.0000x reference)
//
#include <hip/hip_runtime.h>
#include <cstdint>
#include <cstddef>

// Problem constants (from reference setup_inputs)
#define BB 16
#define CC 7
#define HH 368
#define WW 640
#define LL (HH * WW)          // 235520 pixels per batch
#define NCLS 6                // classes 1..6 (background 0 skipped)
#define NCOMBO (BB * NCLS)    // 96

// ---------------------------------------------------------------------------
// Kernel 1: seg[b, i] = (uint8) floor( soft_argmax(logits[b, :, i]) )
// 4 pixels per thread -> float4 loads per channel (16B/lane, coalesced).
// Softmax mimics jax.nn.softmax: e_c = exp(x_c - max), p_c = e_c / sum,
// acc = sum p_c * c in channel order.
// ---------------------------------------------------------------------------
__global__ __launch_bounds__(256) void seg_kernel(const float* __restrict__ logits,
                                                  uint8_t* __restrict__ seg) {
    const int NG  = (BB * LL) / 4;         // 942080 groups of 4 pixels
    const int GPB = LL / 4;                // groups per batch (LL % 4 == 0)
    int g = blockIdx.x * blockDim.x + threadIdx.x;
    if (g >= NG) return;
    int b = g / GPB;
    int i = (g - b * GPB) * 4;             // pixel index within batch, 16B aligned
    const float* base = logits + (size_t)b * CC * LL + i;

    float x[CC][4];
#pragma unroll
    for (int c = 0; c < CC; ++c) {
        float4 v = *reinterpret_cast<const float4*>(base + (size_t)c * LL);
        x[c][0] = v.x; x[c][1] = v.y; x[c][2] = v.z; x[c][3] = v.w;
    }

    uint8_t outb[4];
#pragma unroll
    for (int k = 0; k < 4; ++k) {
        float m = x[0][k];
#pragma unroll
        for (int c = 1; c < CC; ++c) m = fmaxf(m, x[c][k]);
        float e[CC];
        float s = 0.0f;
#pragma unroll
        for (int c = 0; c < CC; ++c) { e[c] = expf(x[c][k] - m); s += e[c]; }
        float acc = 0.0f;
#pragma unroll
        for (int c = 0; c < CC; ++c) acc += (e[c] / s) * (float)c;
        outb[k] = (uint8_t)(int)floorf(acc);
    }
    // 4-byte store
    uint32_t packed = (uint32_t)outb[0] | ((uint32_t)outb[1] << 8) |
                      ((uint32_t)outb[2] << 16) | ((uint32_t)outb[3] << 24);
    *reinterpret_cast<uint32_t*>(seg + (size_t)b * LL + i) = packed;
}

// ---------------------------------------------------------------------------
// Kernel 2: per (batch, class) consecutive-masked-pair loss via an
// order-preserving monoid reduce.
// Monoid per contiguous range: (S = sum |d_i - d_prev| over internal pairs,
//                               cnt, first_d, last_d)
// combine(A, B) adds |B.first - A.last| iff both non-empty.
// One block per combo; each thread serially scans a contiguous 920-pixel chunk
// (8-byte word loads), then interleaved-pairs LDS reduce (adjacent ranges only
// -> valid for the non-commutative monoid).
// ---------------------------------------------------------------------------
__global__ __launch_bounds__(256) void pair_kernel(const uint8_t* __restrict__ seg,
                                                   double* __restrict__ partial) {
    const int T  = 256;
    const int CH = LL / T;                 // 920, divisible by 8
    int combo = blockIdx.x;                // 0..95
    int b   = combo / NCLS;
    int cls = 1 + (combo - b * NCLS);      // 1..6
    const uint8_t* sp = seg + (size_t)b * LL;

    int t = threadIdx.x;
    int start = t * CH;

    long long S = 0;
    int cnt = 0, firstd = 0, lastd = 0;
    int row = start / WW;
    int col = start - row * WW;

    const unsigned long long* wp =
        reinterpret_cast<const unsigned long long*>(sp + start);
    for (int w8 = 0; w8 < CH / 8; ++w8) {
        unsigned long long v = wp[w8];
#pragma unroll
        for (int j = 0; j < 8; ++j) {
            int sv = (int)((v >> (8 * j)) & 0xFFull);
            if (sv == cls) {
                int d = col - row;
                if (cnt == 0) firstd = d;
                else          S += (long long)abs(d - lastd);
                lastd = d;
                ++cnt;
            }
            ++col;
            if (col == WW) { col = 0; ++row; }
        }
    }

    __shared__ long long sS[256];
    __shared__ int sC[256], sF[256], sL[256];
    sS[t] = S; sC[t] = cnt; sF[t] = firstd; sL[t] = lastd;
    __syncthreads();

    for (int step = 1; step < T; step <<= 1) {
        if ((t & (2 * step - 1)) == 0) {
            int t2 = t + step;
            int c1 = sC[t], c2 = sC[t2];
            long long Sm = sS[t] + sS[t2] +
                ((c1 > 0 && c2 > 0) ? (long long)abs(sF[t2] - sL[t]) : 0ll);
            int F  = (c1 > 0) ? sF[t] : sF[t2];
            int Ln = (c2 > 0) ? sL[t2] : sL[t];
            sS[t] = Sm; sC[t] = c1 + c2; sF[t] = F; sL[t] = Ln;
        }
        __syncthreads();
    }

    if (t == 0) {
        int n = sC[0];
        double res = 0.0;
        if (n >= 2) {
            // npairs = n-1; mean = S/npairs; result = mean/(n+1)
            res = ((double)sS[0] / (double)(n - 1)) / (double)(n + 1);
        }
        partial[combo] = res;
    }
}

// ---------------------------------------------------------------------------
// Kernel 3: sum the 96 per-combo partials -> out[0] (fp32 scalar).
// ---------------------------------------------------------------------------
__global__ __launch_bounds__(64) void final_kernel(const double* __restrict__ partial,
                                                   float* __restrict__ out) {
    int t = threadIdx.x;   // 64 threads
    double s = 0.0;
    for (int k = t; k < NCOMBO; k += 64) s += partial[k];
#pragma unroll
    for (int off = 32; off > 0; off >>= 1) s += __shfl_down(s, off, 64);
    if (t == 0) out[0] = (float)s;
}

extern "C" void kernel_launch(void* const* d_in, const int* in_sizes, int n_in,
                              void* d_out, int out_size, void* d_ws, size_t ws_size,
                              hipStream_t stream) {
    const float* logits = (const float*)d_in[0];
    // d_in[1] (labels) is unused by the reference computation.
    float* out = (float*)d_out;

    uint8_t* seg     = (uint8_t*)d_ws;
    double*  partial = (double*)((char*)d_ws + (size_t)BB * LL);  // 3768320 B, 8-aligned

    const int NG = (BB * LL) / 4;
    seg_kernel<<<(NG + 255) / 256, 256, 0, stream>>>(logits, seg);
    pair_kernel<<<NCOMBO, 256, 0, stream>>>(seg, partial);
    final_kernel<<<1, 64, 0, stream>>>(partial, out);
}

// Round 2
// 169.979 us; speedup vs baseline: 1.4301x; 1.4301x over previous
//
#include <hip/hip_runtime.h>
#include <cstdint>
#include <cstddef>

// Problem constants (from reference setup_inputs)
#define BB 16
#define CC 7
#define HH 368
#define WW 640
#define LL (HH * WW)          // 235520 pixels per batch
#define NCLS 6                // classes 1..6 (background 0 skipped)
#define NCOMBO (BB * NCLS)    // 96
#define PXB 1024              // pixels per block (256 threads x 4 px)
#define BPB (LL / PXB)        // 230 blocks per batch
#define NBLK (BB * BPB)       // 3680 blocks total

// Order-preserving monoid over a contiguous pixel range (per class):
//   S   = sum of |d_i - d_prev| over consecutive masked pixels inside range
//   cnt = masked pixel count; first/last = d of first/last masked pixel
// Identity: cnt == 0. Combine adds the bridging |B.first - A.last|.
struct St { int S, cnt, first, last; };

__device__ inline St comb(const St& a, const St& b) {
    if (a.cnt == 0) return b;
    if (b.cnt == 0) return a;
    St r;
    r.S     = a.S + b.S + abs(b.first - a.last);
    r.cnt   = a.cnt + b.cnt;
    r.first = a.first;
    r.last  = b.last;
    return r;
}

// ---------------------------------------------------------------------------
// Kernel 1 (fused): soft-argmax -> floor -> per-class monoid scan, one pass.
// Thread t of block (b, bb) owns 4 contiguous pixels; loads 7 float4 (fully
// coalesced: lanes 16B apart per channel). seg never hits memory.
// Block-level interleaved-pairs LDS tree preserves pixel order.
// Output: blkStates[blk][cls] (int4) for stage 2.
// ---------------------------------------------------------------------------
__global__ __launch_bounds__(256) void fused_kernel(const float* __restrict__ logits,
                                                    int4* __restrict__ blkStates) {
    int blk = blockIdx.x;
    int b  = blk / BPB;
    int bb = blk - b * BPB;
    int t  = threadIdx.x;
    int i  = bb * PXB + t * 4;            // pixel index within batch, 16B aligned
    const float* base = logits + (size_t)b * CC * LL + i;

    float x[CC][4];
#pragma unroll
    for (int c = 0; c < CC; ++c) {
        float4 v = *reinterpret_cast<const float4*>(base + (size_t)c * LL);
        x[c][0] = v.x; x[c][1] = v.y; x[c][2] = v.z; x[c][3] = v.w;
    }

    // 4 | 640 and i % 4 == 0 -> the 4-pixel group never crosses a row.
    int row = i / WW;
    int col = i - row * WW;
    int d0  = col - row;

    St st[NCLS];
#pragma unroll
    for (int c = 0; c < NCLS; ++c) { st[c].S = 0; st[c].cnt = 0; st[c].first = 0; st[c].last = 0; }

#pragma unroll
    for (int k = 0; k < 4; ++k) {
        float m = x[0][k];
#pragma unroll
        for (int c = 1; c < CC; ++c) m = fmaxf(m, x[c][k]);
        float s = 0.0f, w = 0.0f;
#pragma unroll
        for (int c = 0; c < CC; ++c) {
            float e = __expf(x[c][k] - m);
            s += e;
            w += e * (float)c;
        }
        // soft_argmax = (sum e_c * c) / (sum e_c); only its floor matters.
        int sv = (int)floorf(__fdividef(w, s));
        int d  = d0 + k;
#pragma unroll
        for (int c = 0; c < NCLS; ++c) {
            if (sv == c + 1) {
                if (st[c].cnt == 0) st[c].first = d;
                else                st[c].S += abs(d - st[c].last);
                st[c].last = d;
                st[c].cnt++;
            }
        }
    }

    __shared__ int4 red[NCLS][256];       // 24 KB
#pragma unroll
    for (int c = 0; c < NCLS; ++c)
        red[c][t] = make_int4(st[c].S, st[c].cnt, st[c].first, st[c].last);
    __syncthreads();

    // Interleaved-pairs tree: combines adjacent ranges only -> order-safe.
    for (int step = 1; step < 256; step <<= 1) {
        if ((t & (2 * step - 1)) == 0) {
#pragma unroll
            for (int c = 0; c < NCLS; ++c) {
                int4 A = red[c][t], B = red[c][t + step];
                St a{A.x, A.y, A.z, A.w}, bs{B.x, B.y, B.z, B.w};
                St r = comb(a, bs);
                red[c][t] = make_int4(r.S, r.cnt, r.first, r.last);
            }
        }
        __syncthreads();
    }

    if (t < NCLS) blkStates[(size_t)blk * NCLS + t] = red[t][0];
}

// ---------------------------------------------------------------------------
// Kernel 2: per (batch, class) combine the 230 per-block states in order.
// 96 blocks x 256 threads; threads >= 230 hold the identity.
// ---------------------------------------------------------------------------
__global__ __launch_bounds__(256) void combine_kernel(const int4* __restrict__ blkStates,
                                                      double* __restrict__ partial) {
    int combo = blockIdx.x;               // b * NCLS + (cls-1)
    int b = combo / NCLS;
    int c = combo - b * NCLS;
    int t = threadIdx.x;

    St st{0, 0, 0, 0};
    if (t < BPB) {
        int4 v = blkStates[(size_t)(b * BPB + t) * NCLS + c];
        st = St{v.x, v.y, v.z, v.w};
    }

    __shared__ int4 red[256];
    red[t] = make_int4(st.S, st.cnt, st.first, st.last);
    __syncthreads();

    for (int step = 1; step < 256; step <<= 1) {
        if ((t & (2 * step - 1)) == 0) {
            int4 A = red[t], B = red[t + step];
            St a{A.x, A.y, A.z, A.w}, bs{B.x, B.y, B.z, B.w};
            St r = comb(a, bs);
            red[t] = make_int4(r.S, r.cnt, r.first, r.last);
        }
        __syncthreads();
    }

    if (t == 0) {
        int n = red[0].y;
        double res = 0.0;
        if (n >= 2) {
            // npairs = n-1; mean = S / npairs; contribution = mean / (n+1)
            res = ((double)red[0].x / (double)(n - 1)) / (double)(n + 1);
        }
        partial[combo] = res;
    }
}

// ---------------------------------------------------------------------------
// Kernel 3: sum 96 per-combo partials -> out[0] (fp32 scalar).
// ---------------------------------------------------------------------------
__global__ __launch_bounds__(64) void final_kernel(const double* __restrict__ partial,
                                                   float* __restrict__ out) {
    int t = threadIdx.x;
    double s = 0.0;
    for (int k = t; k < NCOMBO; k += 64) s += partial[k];
#pragma unroll
    for (int off = 32; off > 0; off >>= 1) s += __shfl_down(s, off, 64);
    if (t == 0) out[0] = (float)s;
}

extern "C" void kernel_launch(void* const* d_in, const int* in_sizes, int n_in,
                              void* d_out, int out_size, void* d_ws, size_t ws_size,
                              hipStream_t stream) {
    const float* logits = (const float*)d_in[0];
    // d_in[1] (labels) is unused by the reference computation.
    float* out = (float*)d_out;

    int4*   blkStates = (int4*)d_ws;                          // 3680*6*16 = 353280 B
    double* partial   = (double*)((char*)d_ws + (size_t)NBLK * NCLS * sizeof(int4));

    fused_kernel<<<NBLK, 256, 0, stream>>>(logits, blkStates);
    combine_kernel<<<NCOMBO, 256, 0, stream>>>(blkStates, partial);
    final_kernel<<<1, 64, 0, stream>>>(partial, out);
}